// Round 3
// baseline (128.052 us; speedup 1.0000x reference)
//
#include <hip/hip_runtime.h>

// Problem constants: N=4096, D=512, C=100, P=64
#define D 512
#define P 64
#define CHUNK 16        // boxes per main block
#define MAXDESC 512     // >= sum_c ceil(m_c/CHUNK) <= 256+100
#define EPS_COS 1e-8f
#define EPS_INV 1e-5f

// ws layout (bytes):
//     0  pp      [6400 f]   ||p||^2 per (class,proto)
// 25600  counts  [128 i]
// 26112  fill    [128 i]
// 26624  base    [128 i]
// 27136  ndesc   [1 i]
// 27200  desc    [3*MAXDESC i]
// 33344  sorted  [4096 i]

__device__ __forceinline__ float wave_sum(float v) {
#pragma unroll
    for (int m = 32; m >= 1; m >>= 1) v += __shfl_xor(v, m, 64);
    return v;
}

// pp[r] = ||protos[r]||^2
__global__ __launch_bounds__(256) void proto_norm_kernel(
    const float* __restrict__ protos, float* __restrict__ pp, int rows)
{
    const int lane = threadIdx.x & 63;
    const int r = blockIdx.x * 4 + (threadIdx.x >> 6);
    if (r >= rows) return;
    const float* row = protos + (size_t)r * D;
    const float4 a = *(const float4*)(row + lane * 4);
    const float4 b = *(const float4*)(row + 256 + lane * 4);
    float s = a.x*a.x + a.y*a.y + a.z*a.z + a.w*a.w
            + b.x*b.x + b.y*b.y + b.z*b.z + b.w*b.w;
    s = wave_sum(s);
    if (lane == 0) pp[r] = s;
}

__global__ __launch_bounds__(256) void hist_kernel(
    const int* __restrict__ cls, int* counts, int N)
{
    const int n = blockIdx.x * 256 + threadIdx.x;
    if (n < N) atomicAdd(&counts[cls[n]], 1);
}

// One wave: exclusive-scan counts (C<=128), build group descriptors.
__global__ __launch_bounds__(64) void scan_desc_kernel(
    const int* __restrict__ counts, int* base, int* desc, int* ndesc, int C)
{
    const int lane = threadIdx.x;
    const int c0 = lane, c1 = lane + 64;
    const int v0 = (c0 < C) ? counts[c0] : 0;
    const int v1 = (c1 < C) ? counts[c1] : 0;
    int s0 = v0, s1 = v1;
#pragma unroll
    for (int d = 1; d < 64; d <<= 1) {
        int t = __shfl_up(s0, d, 64); if (lane >= d) s0 += t;
        t     = __shfl_up(s1, d, 64); if (lane >= d) s1 += t;
    }
    s1 += __shfl(s0, 63, 64);
    const int b0 = s0 - v0, b1 = s1 - v1;
    if (c0 < C) base[c0] = b0;
    if (c1 < C) base[c1] = b1;

    const int g0 = (v0 + CHUNK - 1) / CHUNK, g1 = (v1 + CHUNK - 1) / CHUNK;
    int t0 = g0, t1 = g1;
#pragma unroll
    for (int d = 1; d < 64; d <<= 1) {
        int t = __shfl_up(t0, d, 64); if (lane >= d) t0 += t;
        t     = __shfl_up(t1, d, 64); if (lane >= d) t1 += t;
    }
    t1 += __shfl(t0, 63, 64);
    const int go0 = t0 - g0, go1 = t1 - g1;
    if (lane == 63) ndesc[0] = t1;
    for (int k = 0; k < g0; ++k) {
        const int di = go0 + k;
        desc[3*di] = c0; desc[3*di+1] = b0 + CHUNK*k; desc[3*di+2] = min(CHUNK, v0 - CHUNK*k);
    }
    for (int k = 0; k < g1; ++k) {
        const int di = go1 + k;
        desc[3*di] = c1; desc[3*di+1] = b1 + CHUNK*k; desc[3*di+2] = min(CHUNK, v1 - CHUNK*k);
    }
}

__global__ __launch_bounds__(256) void scatter_kernel(
    const int* __restrict__ cls, const int* __restrict__ base,
    int* fill, int* sorted, int N)
{
    const int n = blockIdx.x * 256 + threadIdx.x;
    if (n < N) {
        const int c = cls[n];
        const int pos = base[c] + atomicAdd(&fill[c], 1);
        sorted[pos] = n;
    }
}

// Main: one block = up to 16 same-class boxes; 4 waves, 4 boxes/wave.
// Protos staged 32 rows at a time in 64KB LDS (2 passes). Reduction tree per
// box identical to R2 (group-of-8 reduce-scatter); lane owns proto
// p = 8*(lane&7) + ((lane>>3)&7).
__global__ __launch_bounds__(256, 2) void proto_main_kernel(
    const float* __restrict__ feats,        // [N, D]
    const float* __restrict__ protos,       // [C, P, D]
    const int*   __restrict__ proto_labels, // [C, P]
    const float* __restrict__ ppbuf,        // [C*P]
    const int*   __restrict__ sorted,       // [N]
    const int*   __restrict__ desc,         // [ndesc][3]
    const int*   __restrict__ ndesc,
    float* __restrict__ out, int N)
{
    __shared__ float tile[32 * D];          // 64 KB
    const int nd = ndesc[0];
    if ((int)blockIdx.x >= nd) return;
    const int cls   = desc[3*blockIdx.x];
    const int start = desc[3*blockIdx.x+1];
    const int cnt   = desc[3*blockIdx.x+2];
    const int lane = threadIdx.x & 63;
    const int wave = threadIdx.x >> 6;

    int  nidx[4];
    bool valid[4];
#pragma unroll
    for (int k = 0; k < 4; ++k) {
        const int pos = wave + 4*k;          // wave-uniform
        valid[k] = pos < cnt;
        nidx[k]  = sorted[start + (valid[k] ? pos : (cnt - 1))];
    }

    float4 f0[4], f1[4];
    float  ff[4];
#pragma unroll
    for (int b = 0; b < 4; ++b) {
        const float* f = feats + (size_t)nidx[b] * D;
        f0[b] = *(const float4*)(f + lane * 4);
        f1[b] = *(const float4*)(f + 256 + lane * 4);
        float s = f0[b].x*f0[b].x + f0[b].y*f0[b].y + f0[b].z*f0[b].z + f0[b].w*f0[b].w
                + f1[b].x*f1[b].x + f1[b].y*f1[b].y + f1[b].z*f1[b].z + f1[b].w*f1[b].w;
        ff[b] = wave_sum(s);
    }

    const float* pr = protos + (size_t)cls * (P * D);
    const int jsel = (lane >> 3) & 7;
    const int gown = lane & 7;
    const bool hi32 = (lane & 32) != 0;
    const bool hi16 = (lane & 16) != 0;
    const bool hi8  = (lane & 8)  != 0;

    float r_dot[4] = {0.f,0.f,0.f,0.f}, r_l1[4] = {0.f,0.f,0.f,0.f};

    for (int pass = 0; pass < 2; ++pass) {
        // stage 32 proto rows -> LDS (coalesced float4)
#pragma unroll
        for (int k = 0; k < 16; ++k) {
            const int idx = threadIdx.x + 256 * k;      // float4 index
            *(float4*)(tile + idx * 4) =
                *(const float4*)(pr + pass * (32 * D) + idx * 4);
        }
        __syncthreads();

        for (int gl = 0; gl < 4; ++gl) {
            const int g = pass * 4 + gl;
            float pd[4][8], pl[4][8];
#pragma unroll
            for (int j = 0; j < 8; ++j) {
                const float* row = tile + (gl * 8 + j) * D;
                const float4 q0 = *(const float4*)(row + lane * 4);
                const float4 q1 = *(const float4*)(row + 256 + lane * 4);
#pragma unroll
                for (int b = 0; b < 4; ++b) {
                    float dot, l1, t;
                    dot  = f0[b].x*q0.x; t = f0[b].x - q0.x; l1  = fabsf(t);
                    dot += f0[b].y*q0.y; t = f0[b].y - q0.y; l1 += fabsf(t);
                    dot += f0[b].z*q0.z; t = f0[b].z - q0.z; l1 += fabsf(t);
                    dot += f0[b].w*q0.w; t = f0[b].w - q0.w; l1 += fabsf(t);
                    dot += f1[b].x*q1.x; t = f1[b].x - q1.x; l1 += fabsf(t);
                    dot += f1[b].y*q1.y; t = f1[b].y - q1.y; l1 += fabsf(t);
                    dot += f1[b].z*q1.z; t = f1[b].z - q1.z; l1 += fabsf(t);
                    dot += f1[b].w*q1.w; t = f1[b].w - q1.w; l1 += fabsf(t);
                    pd[b][j] = dot; pl[b][j] = l1;
                }
            }
            // reduce-scatter: dist 32 (8->4), 16 (4->2), 8 (2->1), butterfly 4,2,1
#pragma unroll
            for (int b = 0; b < 4; ++b) {
#pragma unroll
                for (int k = 0; k < 4; ++k) {
                    const float sd = hi32 ? pd[b][k] : pd[b][k+4];
                    const float sl = hi32 ? pl[b][k] : pl[b][k+4];
                    const float rd = __shfl_xor(sd, 32, 64);
                    const float rl = __shfl_xor(sl, 32, 64);
                    pd[b][k] = (hi32 ? pd[b][k+4] : pd[b][k]) + rd;
                    pl[b][k] = (hi32 ? pl[b][k+4] : pl[b][k]) + rl;
                }
#pragma unroll
                for (int k = 0; k < 2; ++k) {
                    const float sd = hi16 ? pd[b][k] : pd[b][k+2];
                    const float sl = hi16 ? pl[b][k] : pl[b][k+2];
                    const float rd = __shfl_xor(sd, 16, 64);
                    const float rl = __shfl_xor(sl, 16, 64);
                    pd[b][k] = (hi16 ? pd[b][k+2] : pd[b][k]) + rd;
                    pl[b][k] = (hi16 ? pl[b][k+2] : pl[b][k]) + rl;
                }
                {
                    const float sd = hi8 ? pd[b][0] : pd[b][1];
                    const float sl = hi8 ? pl[b][0] : pl[b][1];
                    const float rd = __shfl_xor(sd, 8, 64);
                    const float rl = __shfl_xor(sl, 8, 64);
                    pd[b][0] = (hi8 ? pd[b][1] : pd[b][0]) + rd;
                    pl[b][0] = (hi8 ? pl[b][1] : pl[b][0]) + rl;
                }
#pragma unroll
                for (int m = 4; m >= 1; m >>= 1) {
                    pd[b][0] += __shfl_xor(pd[b][0], m, 64);
                    pl[b][0] += __shfl_xor(pl[b][0], m, 64);
                }
                if (gown == g) { r_dot[b] = pd[b][0]; r_l1[b] = pl[b][0]; }
            }
        }
        __syncthreads();
    }

    const int myp = 8 * gown + jsel;
    const float s_pp = ppbuf[cls * P + myp];

#pragma unroll
    for (int b = 0; b < 4; ++b) {
        const float fnorm = fmaxf(sqrtf(ff[b]), EPS_COS);
        const float pnorm = fmaxf(sqrtf(s_pp),  EPS_COS);
        const float d_cos = 1.0f - r_dot[b] / (fnorm * pnorm);
        const float d_l1  = r_l1[b] * (1.0f / (float)D);
        const float d_l2  = (ff[b] - 2.0f * r_dot[b] + s_pp) * (1.0f / (float)D);

        float s[3];
        s[0] = 1.0f / (d_cos + EPS_INV);
        s[1] = 1.0f / (d_l1  + EPS_INV);
        s[2] = 1.0f / (d_l2  + EPS_INV);

        float prob = 0.f;
#pragma unroll
        for (int i = 0; i < 3; ++i) {
            float m = s[i];
#pragma unroll
            for (int w = 32; w >= 1; w >>= 1) m = fmaxf(m, __shfl_xor(m, w, 64));
            const float e = expf(s[i] - m);
            prob += e / wave_sum(e);
        }
        prob *= (1.0f / 3.0f);

        float best = prob;
        int   bidx = myp;
#pragma unroll
        for (int w = 32; w >= 1; w >>= 1) {
            const float ov = __shfl_xor(best, w, 64);
            const int   oi = __shfl_xor(bidx, w, 64);
            if (ov > best || (ov == best && oi < bidx)) { best = ov; bidx = oi; }
        }

        if (valid[b]) {
            out[(size_t)N + (size_t)nidx[b] * P + myp] = prob;
            if (lane == 0) out[nidx[b]] = (float)proto_labels[cls * P + bidx];
        }
    }
}

extern "C" void kernel_launch(void* const* d_in, const int* in_sizes, int n_in,
                              void* d_out, int out_size, void* d_ws, size_t ws_size,
                              hipStream_t stream) {
    const float* feats        = (const float*)d_in[0];
    const float* protos       = (const float*)d_in[1];
    const int*   cls_ids      = (const int*)d_in[2];
    const int*   proto_labels = (const int*)d_in[3];
    float* out = (float*)d_out;

    const int N    = in_sizes[2];            // 4096
    const int rows = in_sizes[1] / D;        // C*P
    const int C    = rows / P;               // 100

    char* w = (char*)d_ws;
    float* pp     = (float*)w;
    int*   counts = (int*)(w + 25600);
    int*   fill   = (int*)(w + 26112);
    int*   base   = (int*)(w + 26624);
    int*   ndesc  = (int*)(w + 27136);
    int*   desc   = (int*)(w + 27200);
    int*   sorted = (int*)(w + 33344);

    hipMemsetAsync(counts, 0, 1024, stream);  // counts + fill
    proto_norm_kernel<<<(rows + 3) / 4, 256, 0, stream>>>(protos, pp, rows);
    hist_kernel<<<(N + 255) / 256, 256, 0, stream>>>(cls_ids, counts, N);
    scan_desc_kernel<<<1, 64, 0, stream>>>(counts, base, desc, ndesc, C);
    scatter_kernel<<<(N + 255) / 256, 256, 0, stream>>>(cls_ids, base, fill, sorted, N);
    proto_main_kernel<<<MAXDESC, 256, 0, stream>>>(
        feats, protos, proto_labels, pp, sorted, desc, ndesc, out, N);
}

// Round 4
// 123.315 us; speedup vs baseline: 1.0384x; 1.0384x over previous
//
#include <hip/hip_runtime.h>

// Problem constants: N=4096, D=512, C=100, P=64
#define D 512
#define P 64
#define CHUNK 16        // boxes per main block
#define MAXDESC 384     // >= C + N/CHUNK = 100 + 256
#define EPS_COS 1e-8f
#define EPS_INV 1e-5f

// ws layout (bytes):
//     0  pp      [6400 f]
// 25600  sorted  [4096 i]
// 41984  desc    [3*MAXDESC i]
// 46592  ndesc   [1 i]

__device__ __forceinline__ float wave_sum(float v) {
#pragma unroll
    for (int m = 32; m >= 1; m >>= 1) v += __shfl_xor(v, m, 64);
    return v;
}

// pp[r] = ||protos[r]||^2
__global__ __launch_bounds__(256) void proto_norm_kernel(
    const float* __restrict__ protos, float* __restrict__ pp, int rows)
{
    const int lane = threadIdx.x & 63;
    const int r = blockIdx.x * 4 + (threadIdx.x >> 6);
    if (r >= rows) return;
    const float* row = protos + (size_t)r * D;
    const float4 a = *(const float4*)(row + lane * 4);
    const float4 b = *(const float4*)(row + 256 + lane * 4);
    float s = a.x*a.x + a.y*a.y + a.z*a.z + a.w*a.w
            + b.x*b.x + b.y*b.y + b.z*b.z + b.w*b.w;
    s = wave_sum(s);
    if (lane == 0) pp[r] = s;
}

// Single block: histogram + scan + descriptor build + scatter, all via LDS.
__global__ __launch_bounds__(1024) void setup_kernel(
    const int* __restrict__ cls, int* __restrict__ sorted,
    int* __restrict__ desc, int* __restrict__ ndesc, int N, int C)
{
    __shared__ int cnt[128], fl[128], exc[128], gexc[128];
    const int t = threadIdx.x;
    if (t < 128) { cnt[t] = 0; fl[t] = 0; }
    __syncthreads();
#pragma unroll
    for (int k = 0; k < 4; ++k) {
        const int n = t + 1024 * k;
        if (n < N) atomicAdd(&cnt[cls[n]], 1);
    }
    __syncthreads();
    int v = 0, gv = 0;
    if (t < 128) { v = cnt[t]; gv = (v + CHUNK - 1) / CHUNK; exc[t] = v; gexc[t] = gv; }
    __syncthreads();
    for (int d = 1; d < 128; d <<= 1) {          // inclusive Hillis-Steele
        int a = 0, b = 0;
        if (t < 128 && t >= d) { a = exc[t - d]; b = gexc[t - d]; }
        __syncthreads();
        if (t < 128 && t >= d) { exc[t] += a; gexc[t] += b; }
        __syncthreads();
    }
    int base = 0, gbase = 0;
    if (t < 128) { base = exc[t] - v; gbase = gexc[t] - gv; }
    if (t == 127) ndesc[0] = gexc[127];
    if (t < 128) exc[t] = base;                  // own-slot rewrite, no hazard
    __syncthreads();
    if (t < C) {
        for (int k = 0; k < gv; ++k) {
            desc[3*(gbase+k)+0] = t;
            desc[3*(gbase+k)+1] = base + CHUNK*k;
            desc[3*(gbase+k)+2] = min(CHUNK, v - CHUNK*k);
        }
    }
#pragma unroll
    for (int k = 0; k < 4; ++k) {
        const int n = t + 1024 * k;
        if (n < N) {
            const int c = cls[n];
            const int pos = exc[c] + atomicAdd(&fl[c], 1);
            sorted[pos] = n;
        }
    }
}

// Main: block = 512 thr (8 waves) = 16 same-class boxes.
// wave w: box-group bg=w&3 (boxes bg,bg+4,bg+8,bg+12), proto-half h=w>>2.
// 4 staging passes of 16 proto rows (32 KB tile); per pass wave processes its
// 8 rows (protos 16*pass + 8*h + j). Reduce tree identical to R3 (bit-exact).
// Lane keep: (lane&3)==pass -> lane owns proto pg = 16*(lane&3)+8*h+((lane>>3)&7),
// quantity by (lane>>2)&1 (dot / l1). Halves combined in LDS dist buffer,
// then block-level softmax with lane == proto index.
__global__ __launch_bounds__(512, 2) void proto_main_kernel(
    const float* __restrict__ feats,        // [N, D]
    const float* __restrict__ protos,       // [C, P, D]
    const int*   __restrict__ proto_labels, // [C, P]
    const float* __restrict__ ppbuf,        // [C*P]
    const int*   __restrict__ sorted,       // [N]
    const int*   __restrict__ desc,         // [ndesc][3]
    const int*   __restrict__ ndesc,
    float* __restrict__ out, int N)
{
    __shared__ float tile[16 * D];          // 32 KB
    __shared__ float dist[CHUNK * P * 2];   // 8 KB: [box][proto][dot,l1]
    __shared__ float ffbuf[CHUNK];

    if ((int)blockIdx.x >= ndesc[0]) return;
    const int cls   = desc[3*blockIdx.x];
    const int start = desc[3*blockIdx.x+1];
    const int cnt   = desc[3*blockIdx.x+2];
    const int tid  = threadIdx.x;
    const int lane = tid & 63;
    const int wave = tid >> 6;
    const int bg = wave & 3;
    const int h  = wave >> 2;

    int nidx[4];
#pragma unroll
    for (int k = 0; k < 4; ++k) {
        const int pos = bg + 4*k;
        nidx[k] = sorted[start + (pos < cnt ? pos : cnt - 1)];
    }

    float4 f0[4], f1[4];
    float  ff[4];
#pragma unroll
    for (int b = 0; b < 4; ++b) {
        const float* f = feats + (size_t)nidx[b] * D;
        f0[b] = *(const float4*)(f + lane * 4);
        f1[b] = *(const float4*)(f + 256 + lane * 4);
        float s = f0[b].x*f0[b].x + f0[b].y*f0[b].y + f0[b].z*f0[b].z + f0[b].w*f0[b].w
                + f1[b].x*f1[b].x + f1[b].y*f1[b].y + f1[b].z*f1[b].z + f1[b].w*f1[b].w;
        ff[b] = wave_sum(s);
    }
    if (h == 0 && lane == 0) {
#pragma unroll
        for (int k = 0; k < 4; ++k) ffbuf[bg + 4*k] = ff[k];
    }

    const float* pr = protos + (size_t)cls * (P * D);
    const bool hi32 = (lane & 32) != 0;
    const bool hi16 = (lane & 16) != 0;
    const bool hi8  = (lane & 8)  != 0;

    float r_dot[4] = {0.f,0.f,0.f,0.f}, r_l1[4] = {0.f,0.f,0.f,0.f};

    for (int pass = 0; pass < 4; ++pass) {
        if (pass) __syncthreads();          // tile readers done before overwrite
#pragma unroll
        for (int i = 0; i < 4; ++i) {       // stage 16 rows, coalesced float4
            const int idx = tid + 512 * i;
            *(float4*)(tile + idx * 4) =
                *(const float4*)(pr + pass * (16 * D) + idx * 4);
        }
        __syncthreads();

        float pd[4][8], pl[4][8];
#pragma unroll
        for (int j = 0; j < 8; ++j) {
            const float* row = tile + (8 * h + j) * D;
            const float4 q0 = *(const float4*)(row + lane * 4);
            const float4 q1 = *(const float4*)(row + 256 + lane * 4);
#pragma unroll
            for (int b = 0; b < 4; ++b) {
                float dot, l1, t;
                dot  = f0[b].x*q0.x; t = f0[b].x - q0.x; l1  = fabsf(t);
                dot += f0[b].y*q0.y; t = f0[b].y - q0.y; l1 += fabsf(t);
                dot += f0[b].z*q0.z; t = f0[b].z - q0.z; l1 += fabsf(t);
                dot += f0[b].w*q0.w; t = f0[b].w - q0.w; l1 += fabsf(t);
                dot += f1[b].x*q1.x; t = f1[b].x - q1.x; l1 += fabsf(t);
                dot += f1[b].y*q1.y; t = f1[b].y - q1.y; l1 += fabsf(t);
                dot += f1[b].z*q1.z; t = f1[b].z - q1.z; l1 += fabsf(t);
                dot += f1[b].w*q1.w; t = f1[b].w - q1.w; l1 += fabsf(t);
                pd[b][j] = dot; pl[b][j] = l1;
            }
        }
#pragma unroll
        for (int b = 0; b < 4; ++b) {
#pragma unroll
            for (int k = 0; k < 4; ++k) {
                const float sd = hi32 ? pd[b][k] : pd[b][k+4];
                const float sl = hi32 ? pl[b][k] : pl[b][k+4];
                const float rd = __shfl_xor(sd, 32, 64);
                const float rl = __shfl_xor(sl, 32, 64);
                pd[b][k] = (hi32 ? pd[b][k+4] : pd[b][k]) + rd;
                pl[b][k] = (hi32 ? pl[b][k+4] : pl[b][k]) + rl;
            }
#pragma unroll
            for (int k = 0; k < 2; ++k) {
                const float sd = hi16 ? pd[b][k] : pd[b][k+2];
                const float sl = hi16 ? pl[b][k] : pl[b][k+2];
                const float rd = __shfl_xor(sd, 16, 64);
                const float rl = __shfl_xor(sl, 16, 64);
                pd[b][k] = (hi16 ? pd[b][k+2] : pd[b][k]) + rd;
                pl[b][k] = (hi16 ? pl[b][k+2] : pl[b][k]) + rl;
            }
            {
                const float sd = hi8 ? pd[b][0] : pd[b][1];
                const float sl = hi8 ? pl[b][0] : pl[b][1];
                const float rd = __shfl_xor(sd, 8, 64);
                const float rl = __shfl_xor(sl, 8, 64);
                pd[b][0] = (hi8 ? pd[b][1] : pd[b][0]) + rd;
                pl[b][0] = (hi8 ? pl[b][1] : pl[b][0]) + rl;
            }
#pragma unroll
            for (int m = 4; m >= 1; m >>= 1) {
                pd[b][0] += __shfl_xor(pd[b][0], m, 64);
                pl[b][0] += __shfl_xor(pl[b][0], m, 64);
            }
            if ((lane & 3) == pass) { r_dot[b] = pd[b][0]; r_l1[b] = pl[b][0]; }
        }
    }

    // write owned (proto, quantity) results for 4 boxes
    {
        const int pg   = 16 * (lane & 3) + 8 * h + ((lane >> 3) & 7);
        const int qsel = (lane >> 2) & 1;
#pragma unroll
        for (int k = 0; k < 4; ++k) {
            dist[((bg + 4*k) * P + pg) * 2 + qsel] = qsel ? r_l1[k] : r_dot[k];
        }
    }
    __syncthreads();

    // softmax phase: wave handles box slots 2*wave, 2*wave+1; lane == proto
    const float ppv   = ppbuf[cls * P + lane];
    const float pnorm = fmaxf(sqrtf(ppv), EPS_COS);

#pragma unroll
    for (int kk = 0; kk < 2; ++kk) {
        const int s = 2 * wave + kk;
        if (s >= cnt) continue;                     // wave-uniform
        const int n = sorted[start + s];
        const float2 dl = *(const float2*)&dist[(s * P + lane) * 2];
        const float ffv   = ffbuf[s];
        const float fnorm = fmaxf(sqrtf(ffv), EPS_COS);
        const float d_cos = 1.0f - dl.x / (fnorm * pnorm);
        const float d_l1  = dl.y * (1.0f / (float)D);
        const float d_l2  = (ffv - 2.0f * dl.x + ppv) * (1.0f / (float)D);

        float sc[3];
        sc[0] = 1.0f / (d_cos + EPS_INV);
        sc[1] = 1.0f / (d_l1  + EPS_INV);
        sc[2] = 1.0f / (d_l2  + EPS_INV);

        float prob = 0.f;
#pragma unroll
        for (int i = 0; i < 3; ++i) {
            float m = sc[i];
#pragma unroll
            for (int w = 32; w >= 1; w >>= 1) m = fmaxf(m, __shfl_xor(m, w, 64));
            const float e = expf(sc[i] - m);
            prob += e / wave_sum(e);
        }
        prob *= (1.0f / 3.0f);

        float best = prob;
        int   bidx = lane;
#pragma unroll
        for (int w = 32; w >= 1; w >>= 1) {
            const float ov = __shfl_xor(best, w, 64);
            const int   oi = __shfl_xor(bidx, w, 64);
            if (ov > best || (ov == best && oi < bidx)) { best = ov; bidx = oi; }
        }

        out[(size_t)N + (size_t)n * P + lane] = prob;
        if (lane == 0) out[n] = (float)proto_labels[cls * P + bidx];
    }
}

extern "C" void kernel_launch(void* const* d_in, const int* in_sizes, int n_in,
                              void* d_out, int out_size, void* d_ws, size_t ws_size,
                              hipStream_t stream) {
    const float* feats        = (const float*)d_in[0];
    const float* protos       = (const float*)d_in[1];
    const int*   cls_ids      = (const int*)d_in[2];
    const int*   proto_labels = (const int*)d_in[3];
    float* out = (float*)d_out;

    const int N    = in_sizes[2];            // 4096
    const int rows = in_sizes[1] / D;        // C*P
    const int C    = rows / P;               // 100

    char* w = (char*)d_ws;
    float* pp     = (float*)w;
    int*   sorted = (int*)(w + 25600);
    int*   desc   = (int*)(w + 41984);
    int*   ndesc  = (int*)(w + 46592);

    proto_norm_kernel<<<(rows + 3) / 4, 256, 0, stream>>>(protos, pp, rows);
    setup_kernel<<<1, 1024, 0, stream>>>(cls_ids, sorted, desc, ndesc, N, C);
    proto_main_kernel<<<MAXDESC, 512, 0, stream>>>(
        feats, protos, proto_labels, pp, sorted, desc, ndesc, out, N);
}

// Round 5
// 119.799 us; speedup vs baseline: 1.0689x; 1.0294x over previous
//
#include <hip/hip_runtime.h>

// Problem constants: N=4096, D=512, C=100, P=64
#define D 512
#define P 64
#define CHUNK 16            // boxes per descriptor
#define MAXD 1152           // >= 4 * worst-case single-bucket chunks (4*281)
#define EPS_COS 1e-8f
#define EPS_INV 1e-5f

// ws layout (bytes):
//     0  pp      [6400 f]
// 25600  sorted  [4096 i]
// 41984  desc    [3*MAXD i]  (13824 B)
// 57344  dist    [N*P*2 f]   (2 MB): [n][proto][dot,l1]

__device__ __forceinline__ float wave_sum(float v) {
#pragma unroll
    for (int m = 32; m >= 1; m >>= 1) v += __shfl_xor(v, m, 64);
    return v;
}

// pp[r] = ||protos[r]||^2
__global__ __launch_bounds__(256) void proto_norm_kernel(
    const float* __restrict__ protos, float* __restrict__ pp, int rows)
{
    const int lane = threadIdx.x & 63;
    const int r = blockIdx.x * 4 + (threadIdx.x >> 6);
    if (r >= rows) return;
    const float* row = protos + (size_t)r * D;
    const float4 a = *(const float4*)(row + lane * 4);
    const float4 b = *(const float4*)(row + 256 + lane * 4);
    float s = a.x*a.x + a.y*a.y + a.z*a.z + a.w*a.w
            + b.x*b.x + b.y*b.y + b.z*b.z + b.w*b.w;
    s = wave_sum(s);
    if (lane == 0) pp[r] = s;
}

// Single block: histogram, box-offset scan, bucket-major chunk scan,
// XCD-interleaved descriptor fill (slot = 4*bucketLocal + (c%4)), scatter.
__global__ __launch_bounds__(1024) void setup_kernel(
    const int* __restrict__ cls, int* __restrict__ sorted,
    int* __restrict__ desc, int N, int C)
{
    __shared__ int cnt[128], fl[128], exc[128], arr[128];
    const int t = threadIdx.x;
    if (t < 128) { cnt[t] = 0; fl[t] = 0; arr[t] = 0; }
    for (int i = t; i < 3 * MAXD; i += 1024) desc[i] = 0;   // cnt=0 everywhere
    __syncthreads();
#pragma unroll
    for (int k = 0; k < 4; ++k) {
        const int n = t + 1024 * k;
        if (n < N) atomicAdd(&cnt[cls[n]], 1);
    }
    __syncthreads();
    int v = 0, gv = 0, pos = 0;
    if (t < 128) {
        v = cnt[t];
        gv = (v + CHUNK - 1) / CHUNK;
        pos = ((t & 3) << 5) | (t >> 2);    // bucket-major position (bijection)
        exc[t] = v;
        arr[pos] = gv;
    }
    __syncthreads();
    for (int d = 1; d < 128; d <<= 1) {     // two inclusive Hillis-Steele scans
        int a = 0, b = 0;
        if (t < 128 && t >= d) { a = exc[t - d]; b = arr[t - d]; }
        __syncthreads();
        if (t < 128 && t >= d) { exc[t] += a; arr[t] += b; }
        __syncthreads();
    }
    int base = 0;
    if (t < 128) base = exc[t] - v;         // exclusive box offset, class order
    __syncthreads();
    if (t < 128) exc[t] = base;
    __syncthreads();
    if (t < C && gv > 0) {
        const int b = t & 3;
        const int bstart = (pos >= 32) ? arr[(pos & ~31) - 1] : 0;  // bucket excl start
        const int localoff = (arr[pos] - gv) - bstart;
        for (int k = 0; k < gv; ++k) {
            const int slot = ((localoff + k) << 2) | b;
            desc[3*slot+0] = t;
            desc[3*slot+1] = base + CHUNK * k;
            desc[3*slot+2] = min(CHUNK, v - CHUNK * k);
        }
    }
#pragma unroll
    for (int k = 0; k < 4; ++k) {
        const int n = t + 1024 * k;
        if (n < N) {
            const int c = cls[n];
            const int p2 = exc[c] + atomicAdd(&fl[c], 1);
            sorted[p2] = n;
        }
    }
}

// Phase 1: block = 4 independent waves, no LDS, no barriers.
// Block B: desc index = B>>1, proto half = B&1. Wave = 4 boxes x 32 protos.
// Reduce tree bit-identical to R2. Lane keeps (group = lane&3, qty = (lane>>2)&1,
// proto-in-group = (lane>>3)&7) -> scatters to dist[n][proto][qty].
__global__ __launch_bounds__(256, 3) void proto_dist_kernel(
    const float* __restrict__ feats,        // [N, D]
    const float* __restrict__ protos,       // [C, P, D]
    const int*   __restrict__ sorted,       // [N]
    const int*   __restrict__ desc,         // [MAXD][3]
    float* __restrict__ dist)               // [N][P][2]
{
    const int di   = blockIdx.x >> 1;
    const int half = blockIdx.x & 1;
    const int cnt  = desc[3*di+2];
    if (cnt == 0) return;
    const int cls   = desc[3*di+0];
    const int start = desc[3*di+1];
    const int lane = threadIdx.x & 63;
    const int wave = threadIdx.x >> 6;

    int  nidx[4];
    bool valid[4];
#pragma unroll
    for (int k = 0; k < 4; ++k) {
        const int pos = wave + 4 * k;       // wave-uniform
        valid[k] = pos < cnt;
        nidx[k]  = sorted[start + (valid[k] ? pos : (cnt - 1))];
    }

    float4 f0[4], f1[4];
#pragma unroll
    for (int b = 0; b < 4; ++b) {
        const float* f = feats + (size_t)nidx[b] * D;
        f0[b] = *(const float4*)(f + lane * 4);
        f1[b] = *(const float4*)(f + 256 + lane * 4);
    }

    const float* pr = protos + (size_t)cls * (P * D) + (size_t)half * (32 * D);
    const bool hi32 = (lane & 32) != 0;
    const bool hi16 = (lane & 16) != 0;
    const bool hi8  = (lane & 8)  != 0;

    float r_dot[4], r_l1[4];

    for (int g = 0; g < 4; ++g) {           // 4 groups of 8 proto rows
        float pd[4][8], pl[4][8];
#pragma unroll
        for (int j = 0; j < 8; ++j) {
            const float* row = pr + (size_t)(8 * g + j) * D;
            const float4 q0 = *(const float4*)(row + lane * 4);
            const float4 q1 = *(const float4*)(row + 256 + lane * 4);
#pragma unroll
            for (int b = 0; b < 4; ++b) {
                float dot, l1, t;
                dot  = f0[b].x*q0.x; t = f0[b].x - q0.x; l1  = fabsf(t);
                dot += f0[b].y*q0.y; t = f0[b].y - q0.y; l1 += fabsf(t);
                dot += f0[b].z*q0.z; t = f0[b].z - q0.z; l1 += fabsf(t);
                dot += f0[b].w*q0.w; t = f0[b].w - q0.w; l1 += fabsf(t);
                dot += f1[b].x*q1.x; t = f1[b].x - q1.x; l1 += fabsf(t);
                dot += f1[b].y*q1.y; t = f1[b].y - q1.y; l1 += fabsf(t);
                dot += f1[b].z*q1.z; t = f1[b].z - q1.z; l1 += fabsf(t);
                dot += f1[b].w*q1.w; t = f1[b].w - q1.w; l1 += fabsf(t);
                pd[b][j] = dot; pl[b][j] = l1;
            }
        }
#pragma unroll
        for (int b = 0; b < 4; ++b) {
#pragma unroll
            for (int k = 0; k < 4; ++k) {
                const float sd = hi32 ? pd[b][k] : pd[b][k+4];
                const float sl = hi32 ? pl[b][k] : pl[b][k+4];
                const float rd = __shfl_xor(sd, 32, 64);
                const float rl = __shfl_xor(sl, 32, 64);
                pd[b][k] = (hi32 ? pd[b][k+4] : pd[b][k]) + rd;
                pl[b][k] = (hi32 ? pl[b][k+4] : pl[b][k]) + rl;
            }
#pragma unroll
            for (int k = 0; k < 2; ++k) {
                const float sd = hi16 ? pd[b][k] : pd[b][k+2];
                const float sl = hi16 ? pl[b][k] : pl[b][k+2];
                const float rd = __shfl_xor(sd, 16, 64);
                const float rl = __shfl_xor(sl, 16, 64);
                pd[b][k] = (hi16 ? pd[b][k+2] : pd[b][k]) + rd;
                pl[b][k] = (hi16 ? pl[b][k+2] : pl[b][k]) + rl;
            }
            {
                const float sd = hi8 ? pd[b][0] : pd[b][1];
                const float sl = hi8 ? pl[b][0] : pl[b][1];
                const float rd = __shfl_xor(sd, 8, 64);
                const float rl = __shfl_xor(sl, 8, 64);
                pd[b][0] = (hi8 ? pd[b][1] : pd[b][0]) + rd;
                pl[b][0] = (hi8 ? pl[b][1] : pl[b][0]) + rl;
            }
#pragma unroll
            for (int m = 4; m >= 1; m >>= 1) {
                pd[b][0] += __shfl_xor(pd[b][0], m, 64);
                pl[b][0] += __shfl_xor(pl[b][0], m, 64);
            }
            if ((lane & 3) == g) { r_dot[b] = pd[b][0]; r_l1[b] = pl[b][0]; }
        }
    }

    const int pg   = 32 * half + 8 * (lane & 3) + ((lane >> 3) & 7);
    const int qsel = (lane >> 2) & 1;
#pragma unroll
    for (int k = 0; k < 4; ++k) {
        if (valid[k]) {
            dist[((size_t)nidx[k] * P + pg) * 2 + qsel] = qsel ? r_l1[k] : r_dot[k];
        }
    }
}

// Phase 2: one wave per box; lane == proto. Softmax/argmax epilogue (as R4).
__global__ __launch_bounds__(256) void softmax_kernel(
    const float* __restrict__ feats,        // [N, D]
    const int*   __restrict__ cls_ids,      // [N]
    const int*   __restrict__ proto_labels, // [C, P]
    const float* __restrict__ ppbuf,        // [C*P]
    const float* __restrict__ dist,         // [N][P][2]
    float* __restrict__ out, int N)
{
    const int lane = threadIdx.x & 63;
    const int n = blockIdx.x * 4 + (threadIdx.x >> 6);
    if (n >= N) return;
    const int cls = cls_ids[n];

    const float* f = feats + (size_t)n * D;
    const float4 a = *(const float4*)(f + lane * 4);
    const float4 b = *(const float4*)(f + 256 + lane * 4);
    float ffv = a.x*a.x + a.y*a.y + a.z*a.z + a.w*a.w
              + b.x*b.x + b.y*b.y + b.z*b.z + b.w*b.w;
    ffv = wave_sum(ffv);

    const float2 dl = *(const float2*)&dist[((size_t)n * P + lane) * 2];
    const float ppv   = ppbuf[cls * P + lane];
    const float fnorm = fmaxf(sqrtf(ffv), EPS_COS);
    const float pnorm = fmaxf(sqrtf(ppv), EPS_COS);
    const float d_cos = 1.0f - dl.x / (fnorm * pnorm);
    const float d_l1  = dl.y * (1.0f / (float)D);
    const float d_l2  = (ffv - 2.0f * dl.x + ppv) * (1.0f / (float)D);

    float sc[3];
    sc[0] = 1.0f / (d_cos + EPS_INV);
    sc[1] = 1.0f / (d_l1  + EPS_INV);
    sc[2] = 1.0f / (d_l2  + EPS_INV);

    float prob = 0.f;
#pragma unroll
    for (int i = 0; i < 3; ++i) {
        float m = sc[i];
#pragma unroll
        for (int w = 32; w >= 1; w >>= 1) m = fmaxf(m, __shfl_xor(m, w, 64));
        const float e = expf(sc[i] - m);
        prob += e / wave_sum(e);
    }
    prob *= (1.0f / 3.0f);

    float best = prob;
    int   bidx = lane;
#pragma unroll
    for (int w = 32; w >= 1; w >>= 1) {
        const float ov = __shfl_xor(best, w, 64);
        const int   oi = __shfl_xor(bidx, w, 64);
        if (ov > best || (ov == best && oi < bidx)) { best = ov; bidx = oi; }
    }

    out[(size_t)N + (size_t)n * P + lane] = prob;
    if (lane == 0) out[n] = (float)proto_labels[cls * P + bidx];
}

extern "C" void kernel_launch(void* const* d_in, const int* in_sizes, int n_in,
                              void* d_out, int out_size, void* d_ws, size_t ws_size,
                              hipStream_t stream) {
    const float* feats        = (const float*)d_in[0];
    const float* protos       = (const float*)d_in[1];
    const int*   cls_ids      = (const int*)d_in[2];
    const int*   proto_labels = (const int*)d_in[3];
    float* out = (float*)d_out;

    const int N    = in_sizes[2];            // 4096
    const int rows = in_sizes[1] / D;        // C*P
    const int C    = rows / P;               // 100

    char* w = (char*)d_ws;
    float* pp     = (float*)w;
    int*   sorted = (int*)(w + 25600);
    int*   desc   = (int*)(w + 41984);
    float* dist   = (float*)(w + 57344);

    proto_norm_kernel<<<(rows + 3) / 4, 256, 0, stream>>>(protos, pp, rows);
    setup_kernel<<<1, 1024, 0, stream>>>(cls_ids, sorted, desc, N, C);
    proto_dist_kernel<<<2 * MAXD, 256, 0, stream>>>(feats, protos, sorted, desc, dist);
    softmax_kernel<<<(N + 3) / 4, 256, 0, stream>>>(
        feats, cls_ids, proto_labels, pp, dist, out, N);
}

// Round 6
// 114.180 us; speedup vs baseline: 1.1215x; 1.0492x over previous
//
#include <hip/hip_runtime.h>

// Problem constants: N=4096, D=512, C=100, P=64
#define D 512
#define P 64
#define CHUNK 4             // boxes per descriptor (2 waves x 2 boxes)
#define MAXD 1536           // 8 buckets x 192 chunk slots
#define EPS_COS 1e-8f
#define EPS_INV 1e-5f

// ws layout (bytes):
//     0  pp      [6400 f]
// 25600  sorted  [4096 i]
// 41984  desc    [3*MAXD i] (18432 B)

__device__ __forceinline__ float wave_sum(float v) {
#pragma unroll
    for (int m = 32; m >= 1; m >>= 1) v += __shfl_xor(v, m, 64);
    return v;
}

// Block 0: histogram + scans + XCD-interleaved descriptor fill + scatter.
// Blocks 1..: pp[r] = ||protos[r]||^2 (4 rows per block).
__global__ __launch_bounds__(256) void prep_kernel(
    const float* __restrict__ protos, const int* __restrict__ cls,
    float* __restrict__ pp, int* __restrict__ sorted, int* __restrict__ desc,
    int N, int C, int rows)
{
    if (blockIdx.x != 0) {
        const int lane = threadIdx.x & 63;
        const int r = (blockIdx.x - 1) * 4 + (threadIdx.x >> 6);
        if (r >= rows) return;
        const float* row = protos + (size_t)r * D;
        const float4 a = *(const float4*)(row + lane * 4);
        const float4 b = *(const float4*)(row + 256 + lane * 4);
        float s = a.x*a.x + a.y*a.y + a.z*a.z + a.w*a.w
                + b.x*b.x + b.y*b.y + b.z*b.z + b.w*b.w;
        s = wave_sum(s);
        if (lane == 0) pp[r] = s;
        return;
    }

    __shared__ int cnt[128], fl[128], exc[128], arr[128];
    const int t = threadIdx.x;
    if (t < 128) { cnt[t] = 0; fl[t] = 0; arr[t] = 0; }
    for (int i = t; i < 3 * MAXD; i += 256) desc[i] = 0;   // cnt=0 everywhere
    __syncthreads();
#pragma unroll
    for (int k = 0; k < 16; ++k) {
        const int n = t + 256 * k;
        if (n < N) atomicAdd(&cnt[cls[n]], 1);
    }
    __syncthreads();
    int v = 0, gv = 0, pos = 0;
    if (t < 128) {
        v = cnt[t];
        gv = (v + CHUNK - 1) / CHUNK;
        pos = ((t & 7) << 4) | (t >> 3);    // bucket-major bijection
        exc[t] = v;
        arr[pos] = gv;
    }
    __syncthreads();
    for (int d = 1; d < 128; d <<= 1) {     // two inclusive scans
        int a = 0, b = 0;
        if (t < 128 && t >= d) { a = exc[t - d]; b = arr[t - d]; }
        __syncthreads();
        if (t < 128 && t >= d) { exc[t] += a; arr[t] += b; }
        __syncthreads();
    }
    const int base = (t < 128) ? exc[t] - v : 0;
    __syncthreads();
    if (t < 128) exc[t] = base;
    __syncthreads();
    if (t < C && gv > 0) {
        const int bucket = t & 7;
        const int bstart = bucket ? arr[(bucket << 4) - 1] : 0;
        const int localoff = (arr[pos] - gv) - bstart;
        for (int k = 0; k < gv; ++k) {
            const int slot = ((localoff + k) << 3) | bucket;
            if (slot < MAXD) {
                desc[3*slot+0] = t;
                desc[3*slot+1] = base + CHUNK * k;
                desc[3*slot+2] = min(CHUNK, v - CHUNK * k);
            }
        }
    }
#pragma unroll
    for (int k = 0; k < 16; ++k) {
        const int n = t + 256 * k;
        if (n < N) {
            const int c = cls[n];
            const int p2 = exc[c] + atomicAdd(&fl[c], 1);
            sorted[p2] = n;
        }
    }
}

// Fused main: block = 128 thr (2 waves), desc = 4 same-class boxes, wave = 2
// boxes x 64 protos. No LDS, no barriers. Distance tree = R2's verified
// 8-group reduce-scatter (bit-exact); lane owns proto myp=8*(lane&7)+((lane>>3)&7).
// Epilogue = R2's verified softmax/argmax, inline per box.
__global__ __launch_bounds__(128) void proto_main_kernel(
    const float* __restrict__ feats,        // [N, D]
    const float* __restrict__ protos,       // [C, P, D]
    const int*   __restrict__ proto_labels, // [C, P]
    const float* __restrict__ ppbuf,        // [C*P]
    const int*   __restrict__ sorted,       // [N]
    const int*   __restrict__ desc,         // [MAXD][3]
    float* __restrict__ out, int N)
{
    const int di  = blockIdx.x;
    const int cnt = desc[3*di+2];
    if (cnt == 0) return;
    const int cls   = desc[3*di+0];
    const int start = desc[3*di+1];
    const int lane = threadIdx.x & 63;
    const int wave = threadIdx.x >> 6;

    int  nidx[2];
    bool valid[2];
#pragma unroll
    for (int k = 0; k < 2; ++k) {
        const int pos = wave + 2 * k;       // wave-uniform
        valid[k] = pos < cnt;
        nidx[k]  = sorted[start + (valid[k] ? pos : (cnt - 1))];
    }

    float4 f0[2], f1[2];
    float  ff[2];
#pragma unroll
    for (int b = 0; b < 2; ++b) {
        const float* f = feats + (size_t)nidx[b] * D;
        f0[b] = *(const float4*)(f + lane * 4);
        f1[b] = *(const float4*)(f + 256 + lane * 4);
        float s = f0[b].x*f0[b].x + f0[b].y*f0[b].y + f0[b].z*f0[b].z + f0[b].w*f0[b].w
                + f1[b].x*f1[b].x + f1[b].y*f1[b].y + f1[b].z*f1[b].z + f1[b].w*f1[b].w;
        ff[b] = wave_sum(s);
    }

    const float* pr = protos + (size_t)cls * (P * D);
    const int jsel = (lane >> 3) & 7;
    const int gown = lane & 7;
    const bool hi32 = (lane & 32) != 0;
    const bool hi16 = (lane & 16) != 0;
    const bool hi8  = (lane & 8)  != 0;

    float r_dot[2] = {0.f, 0.f}, r_l1[2] = {0.f, 0.f};

    for (int g = 0; g < 8; ++g) {           // 8 groups of 8 proto rows
        float pd[2][8], pl[2][8];
#pragma unroll
        for (int j = 0; j < 8; ++j) {
            const float* row = pr + (size_t)(8 * g + j) * D;
            const float4 q0 = *(const float4*)(row + lane * 4);
            const float4 q1 = *(const float4*)(row + 256 + lane * 4);
#pragma unroll
            for (int b = 0; b < 2; ++b) {
                float dot, l1, t;
                dot  = f0[b].x*q0.x; t = f0[b].x - q0.x; l1  = fabsf(t);
                dot += f0[b].y*q0.y; t = f0[b].y - q0.y; l1 += fabsf(t);
                dot += f0[b].z*q0.z; t = f0[b].z - q0.z; l1 += fabsf(t);
                dot += f0[b].w*q0.w; t = f0[b].w - q0.w; l1 += fabsf(t);
                dot += f1[b].x*q1.x; t = f1[b].x - q1.x; l1 += fabsf(t);
                dot += f1[b].y*q1.y; t = f1[b].y - q1.y; l1 += fabsf(t);
                dot += f1[b].z*q1.z; t = f1[b].z - q1.z; l1 += fabsf(t);
                dot += f1[b].w*q1.w; t = f1[b].w - q1.w; l1 += fabsf(t);
                pd[b][j] = dot; pl[b][j] = l1;
            }
        }
#pragma unroll
        for (int b = 0; b < 2; ++b) {
#pragma unroll
            for (int k = 0; k < 4; ++k) {
                const float sd = hi32 ? pd[b][k] : pd[b][k+4];
                const float sl = hi32 ? pl[b][k] : pl[b][k+4];
                const float rd = __shfl_xor(sd, 32, 64);
                const float rl = __shfl_xor(sl, 32, 64);
                pd[b][k] = (hi32 ? pd[b][k+4] : pd[b][k]) + rd;
                pl[b][k] = (hi32 ? pl[b][k+4] : pl[b][k]) + rl;
            }
#pragma unroll
            for (int k = 0; k < 2; ++k) {
                const float sd = hi16 ? pd[b][k] : pd[b][k+2];
                const float sl = hi16 ? pl[b][k] : pl[b][k+2];
                const float rd = __shfl_xor(sd, 16, 64);
                const float rl = __shfl_xor(sl, 16, 64);
                pd[b][k] = (hi16 ? pd[b][k+2] : pd[b][k]) + rd;
                pl[b][k] = (hi16 ? pl[b][k+2] : pl[b][k]) + rl;
            }
            {
                const float sd = hi8 ? pd[b][0] : pd[b][1];
                const float sl = hi8 ? pl[b][0] : pl[b][1];
                const float rd = __shfl_xor(sd, 8, 64);
                const float rl = __shfl_xor(sl, 8, 64);
                pd[b][0] = (hi8 ? pd[b][1] : pd[b][0]) + rd;
                pl[b][0] = (hi8 ? pl[b][1] : pl[b][0]) + rl;
            }
#pragma unroll
            for (int m = 4; m >= 1; m >>= 1) {
                pd[b][0] += __shfl_xor(pd[b][0], m, 64);
                pl[b][0] += __shfl_xor(pl[b][0], m, 64);
            }
            if (gown == g) { r_dot[b] = pd[b][0]; r_l1[b] = pl[b][0]; }
        }
    }

    const int myp = 8 * gown + jsel;
    const float s_pp  = ppbuf[cls * P + myp];
    const float pnorm = fmaxf(sqrtf(s_pp), EPS_COS);

#pragma unroll
    for (int b = 0; b < 2; ++b) {
        const float fnorm = fmaxf(sqrtf(ff[b]), EPS_COS);
        const float d_cos = 1.0f - r_dot[b] / (fnorm * pnorm);
        const float d_l1  = r_l1[b] * (1.0f / (float)D);
        const float d_l2  = (ff[b] - 2.0f * r_dot[b] + s_pp) * (1.0f / (float)D);

        float sc[3];
        sc[0] = 1.0f / (d_cos + EPS_INV);
        sc[1] = 1.0f / (d_l1  + EPS_INV);
        sc[2] = 1.0f / (d_l2  + EPS_INV);

        float prob = 0.f;
#pragma unroll
        for (int i = 0; i < 3; ++i) {
            float m = sc[i];
#pragma unroll
            for (int w = 32; w >= 1; w >>= 1) m = fmaxf(m, __shfl_xor(m, w, 64));
            const float e = expf(sc[i] - m);
            prob += e / wave_sum(e);
        }
        prob *= (1.0f / 3.0f);

        float best = prob;
        int   bidx = myp;
#pragma unroll
        for (int w = 32; w >= 1; w >>= 1) {
            const float ov = __shfl_xor(best, w, 64);
            const int   oi = __shfl_xor(bidx, w, 64);
            if (ov > best || (ov == best && oi < bidx)) { best = ov; bidx = oi; }
        }

        if (valid[b]) {
            out[(size_t)N + (size_t)nidx[b] * P + myp] = prob;
            if (lane == 0) out[nidx[b]] = (float)proto_labels[cls * P + bidx];
        }
    }
}

extern "C" void kernel_launch(void* const* d_in, const int* in_sizes, int n_in,
                              void* d_out, int out_size, void* d_ws, size_t ws_size,
                              hipStream_t stream) {
    const float* feats        = (const float*)d_in[0];
    const float* protos       = (const float*)d_in[1];
    const int*   cls_ids      = (const int*)d_in[2];
    const int*   proto_labels = (const int*)d_in[3];
    float* out = (float*)d_out;

    const int N    = in_sizes[2];            // 4096
    const int rows = in_sizes[1] / D;        // C*P
    const int C    = rows / P;               // 100

    char* w = (char*)d_ws;
    float* pp     = (float*)w;
    int*   sorted = (int*)(w + 25600);
    int*   desc   = (int*)(w + 41984);

    prep_kernel<<<1 + (rows + 3) / 4, 256, 0, stream>>>(
        protos, cls_ids, pp, sorted, desc, N, C, rows);
    proto_main_kernel<<<MAXD, 128, 0, stream>>>(
        feats, protos, proto_labels, pp, sorted, desc, out, N);
}

// Round 7
// 112.982 us; speedup vs baseline: 1.1334x; 1.0106x over previous
//
#include <hip/hip_runtime.h>

// Problem constants: N=4096, D=512, C=100, P=64
#define D 512
#define P 64
#define CHUNK 4             // boxes per descriptor: 2 pairs x 2 halves = 4 waves
#define MAXD 1536           // 8 buckets x 192 chunk slots
#define EPS_COS 1e-8f
#define EPS_INV 1e-5f

// ws layout (bytes):
//     0  pp      [6400 f]
// 25600  sorted  [4096 i]
// 41984  desc    [3*MAXD i] (18432 B)

__device__ __forceinline__ float wave_sum(float v) {
#pragma unroll
    for (int m = 32; m >= 1; m >>= 1) v += __shfl_xor(v, m, 64);
    return v;
}

// Block 0: histogram + scans + XCD-interleaved descriptor fill + scatter.
// Blocks 1..: pp[r] = ||protos[r]||^2 (4 rows per block).
__global__ __launch_bounds__(256) void prep_kernel(
    const float* __restrict__ protos, const int* __restrict__ cls,
    float* __restrict__ pp, int* __restrict__ sorted, int* __restrict__ desc,
    int N, int C, int rows)
{
    if (blockIdx.x != 0) {
        const int lane = threadIdx.x & 63;
        const int r = (blockIdx.x - 1) * 4 + (threadIdx.x >> 6);
        if (r >= rows) return;
        const float* row = protos + (size_t)r * D;
        const float4 a = *(const float4*)(row + lane * 4);
        const float4 b = *(const float4*)(row + 256 + lane * 4);
        float s = a.x*a.x + a.y*a.y + a.z*a.z + a.w*a.w
                + b.x*b.x + b.y*b.y + b.z*b.z + b.w*b.w;
        s = wave_sum(s);
        if (lane == 0) pp[r] = s;
        return;
    }

    __shared__ int cnt[128], fl[128], exc[128], arr[128];
    const int t = threadIdx.x;
    if (t < 128) { cnt[t] = 0; fl[t] = 0; arr[t] = 0; }
    for (int i = t; i < 3 * MAXD; i += 256) desc[i] = 0;   // cnt=0 everywhere
    __syncthreads();
#pragma unroll
    for (int k = 0; k < 16; ++k) {
        const int n = t + 256 * k;
        if (n < N) atomicAdd(&cnt[cls[n]], 1);
    }
    __syncthreads();
    int v = 0, gv = 0, pos = 0;
    if (t < 128) {
        v = cnt[t];
        gv = (v + CHUNK - 1) / CHUNK;
        pos = ((t & 7) << 4) | (t >> 3);    // bucket-major bijection
        exc[t] = v;
        arr[pos] = gv;
    }
    __syncthreads();
    for (int d = 1; d < 128; d <<= 1) {     // two inclusive scans
        int a = 0, b = 0;
        if (t < 128 && t >= d) { a = exc[t - d]; b = arr[t - d]; }
        __syncthreads();
        if (t < 128 && t >= d) { exc[t] += a; arr[t] += b; }
        __syncthreads();
    }
    const int base = (t < 128) ? exc[t] - v : 0;
    __syncthreads();
    if (t < 128) exc[t] = base;
    __syncthreads();
    if (t < C && gv > 0) {
        const int bucket = t & 7;
        const int bstart = bucket ? arr[(bucket << 4) - 1] : 0;
        const int localoff = (arr[pos] - gv) - bstart;
        for (int k = 0; k < gv; ++k) {
            const int slot = ((localoff + k) << 3) | bucket;
            if (slot < MAXD) {
                desc[3*slot+0] = t;
                desc[3*slot+1] = base + CHUNK * k;
                desc[3*slot+2] = min(CHUNK, v - CHUNK * k);
            }
        }
    }
#pragma unroll
    for (int k = 0; k < 16; ++k) {
        const int n = t + 256 * k;
        if (n < N) {
            const int c = cls[n];
            const int p2 = exc[c] + atomicAdd(&fl[c], 1);
            sorted[p2] = n;
        }
    }
}

// Main: block = 256 thr (4 waves) = 4 same-class boxes (2 pairs).
// Wave w: pair p=w>>1 (box slots 2p, 2p+1), proto half h=w&1 (protos 32h..32h+31).
// Each proto row is read ONCE per pair (2-box register reuse) while the grid
// keeps 4096 working waves (~16/CU). Per-half reduce tree = R5's verified
// 4-group reduce-scatter; lane owns (qty=(lane>>2)&1, group=lane&3,
// pig=(lane>>3)&7) -> proto 32h+8*group+pig. Halves meet in a 2KB LDS dist
// buffer; ONE barrier; epilogue wave w = box slot w, lane = proto.
__global__ __launch_bounds__(256, 4) void proto_main_kernel(
    const float* __restrict__ feats,        // [N, D]
    const float* __restrict__ protos,       // [C, P, D]
    const int*   __restrict__ proto_labels, // [C, P]
    const float* __restrict__ ppbuf,        // [C*P]
    const int*   __restrict__ sorted,       // [N]
    const int*   __restrict__ desc,         // [MAXD][3]
    float* __restrict__ out, int N)
{
    __shared__ float dist[CHUNK * P * 2];   // 2 KB: [slot][proto][dot,l1]
    __shared__ float ffbuf[CHUNK];

    const int di  = blockIdx.x;
    const int cnt = desc[3*di+2];
    if (cnt == 0) return;
    const int cls   = desc[3*di+0];
    const int start = desc[3*di+1];
    const int lane = threadIdx.x & 63;
    const int wave = threadIdx.x >> 6;
    const int pair = wave >> 1;             // 0,1
    const int h    = wave & 1;              // proto half

    int nidx[2];
#pragma unroll
    for (int k = 0; k < 2; ++k) {
        const int pos = 2 * pair + k;       // box slot, wave-uniform
        nidx[k] = sorted[start + (pos < cnt ? pos : cnt - 1)];
    }

    float4 f0[2], f1[2];
#pragma unroll
    for (int b = 0; b < 2; ++b) {
        const float* f = feats + (size_t)nidx[b] * D;
        f0[b] = *(const float4*)(f + lane * 4);
        f1[b] = *(const float4*)(f + 256 + lane * 4);
    }
    if (h == 0) {
        float s0 = f0[0].x*f0[0].x + f0[0].y*f0[0].y + f0[0].z*f0[0].z + f0[0].w*f0[0].w
                 + f1[0].x*f1[0].x + f1[0].y*f1[0].y + f1[0].z*f1[0].z + f1[0].w*f1[0].w;
        float s1 = f0[1].x*f0[1].x + f0[1].y*f0[1].y + f0[1].z*f0[1].z + f0[1].w*f0[1].w
                 + f1[1].x*f1[1].x + f1[1].y*f1[1].y + f1[1].z*f1[1].z + f1[1].w*f1[1].w;
        s0 = wave_sum(s0);
        s1 = wave_sum(s1);
        if (lane == 0) { ffbuf[2*pair] = s0; ffbuf[2*pair+1] = s1; }
    }

    const float* pr = protos + (size_t)cls * (P * D) + (size_t)(32 * h) * D;
    const bool hi32 = (lane & 32) != 0;
    const bool hi16 = (lane & 16) != 0;
    const bool hi8  = (lane & 8)  != 0;

    float r_dot[2], r_l1[2];

    for (int g = 0; g < 4; ++g) {           // 4 groups of 8 proto rows
        float pd[2][8], pl[2][8];
#pragma unroll
        for (int j = 0; j < 8; ++j) {
            const float* row = pr + (size_t)(8 * g + j) * D;
            const float4 q0 = *(const float4*)(row + lane * 4);
            const float4 q1 = *(const float4*)(row + 256 + lane * 4);
#pragma unroll
            for (int b = 0; b < 2; ++b) {
                float dot, l1, t;
                dot  = f0[b].x*q0.x; t = f0[b].x - q0.x; l1  = fabsf(t);
                dot += f0[b].y*q0.y; t = f0[b].y - q0.y; l1 += fabsf(t);
                dot += f0[b].z*q0.z; t = f0[b].z - q0.z; l1 += fabsf(t);
                dot += f0[b].w*q0.w; t = f0[b].w - q0.w; l1 += fabsf(t);
                dot += f1[b].x*q1.x; t = f1[b].x - q1.x; l1 += fabsf(t);
                dot += f1[b].y*q1.y; t = f1[b].y - q1.y; l1 += fabsf(t);
                dot += f1[b].z*q1.z; t = f1[b].z - q1.z; l1 += fabsf(t);
                dot += f1[b].w*q1.w; t = f1[b].w - q1.w; l1 += fabsf(t);
                pd[b][j] = dot; pl[b][j] = l1;
            }
        }
#pragma unroll
        for (int b = 0; b < 2; ++b) {
#pragma unroll
            for (int k = 0; k < 4; ++k) {
                const float sd = hi32 ? pd[b][k] : pd[b][k+4];
                const float sl = hi32 ? pl[b][k] : pl[b][k+4];
                const float rd = __shfl_xor(sd, 32, 64);
                const float rl = __shfl_xor(sl, 32, 64);
                pd[b][k] = (hi32 ? pd[b][k+4] : pd[b][k]) + rd;
                pl[b][k] = (hi32 ? pl[b][k+4] : pl[b][k]) + rl;
            }
#pragma unroll
            for (int k = 0; k < 2; ++k) {
                const float sd = hi16 ? pd[b][k] : pd[b][k+2];
                const float sl = hi16 ? pl[b][k] : pl[b][k+2];
                const float rd = __shfl_xor(sd, 16, 64);
                const float rl = __shfl_xor(sl, 16, 64);
                pd[b][k] = (hi16 ? pd[b][k+2] : pd[b][k]) + rd;
                pl[b][k] = (hi16 ? pl[b][k+2] : pl[b][k]) + rl;
            }
            {
                const float sd = hi8 ? pd[b][0] : pd[b][1];
                const float sl = hi8 ? pl[b][0] : pl[b][1];
                const float rd = __shfl_xor(sd, 8, 64);
                const float rl = __shfl_xor(sl, 8, 64);
                pd[b][0] = (hi8 ? pd[b][1] : pd[b][0]) + rd;
                pl[b][0] = (hi8 ? pl[b][1] : pl[b][0]) + rl;
            }
#pragma unroll
            for (int m = 4; m >= 1; m >>= 1) {
                pd[b][0] += __shfl_xor(pd[b][0], m, 64);
                pl[b][0] += __shfl_xor(pl[b][0], m, 64);
            }
            if ((lane & 3) == g) { r_dot[b] = pd[b][0]; r_l1[b] = pl[b][0]; }
        }
    }

    // scatter owned (proto, qty) for this wave's 2 boxes into LDS
    {
        const int pg   = 32 * h + 8 * (lane & 3) + ((lane >> 3) & 7);
        const int qsel = (lane >> 2) & 1;
#pragma unroll
        for (int k = 0; k < 2; ++k) {
            dist[((2 * pair + k) * P + pg) * 2 + qsel] = qsel ? r_l1[k] : r_dot[k];
        }
    }
    __syncthreads();

    // epilogue: wave w = box slot w, lane = proto
    const int s = wave;
    if (s < cnt) {
        const int n = sorted[start + s];
        const float2 dl = *(const float2*)&dist[(s * P + lane) * 2];
        const float ffv   = ffbuf[s];
        const float ppv   = ppbuf[cls * P + lane];
        const float fnorm = fmaxf(sqrtf(ffv), EPS_COS);
        const float pnorm = fmaxf(sqrtf(ppv), EPS_COS);
        const float d_cos = 1.0f - dl.x / (fnorm * pnorm);
        const float d_l1  = dl.y * (1.0f / (float)D);
        const float d_l2  = (ffv - 2.0f * dl.x + ppv) * (1.0f / (float)D);

        float sc[3];
        sc[0] = 1.0f / (d_cos + EPS_INV);
        sc[1] = 1.0f / (d_l1  + EPS_INV);
        sc[2] = 1.0f / (d_l2  + EPS_INV);

        float prob = 0.f;
#pragma unroll
        for (int i = 0; i < 3; ++i) {
            float m = sc[i];
#pragma unroll
            for (int w = 32; w >= 1; w >>= 1) m = fmaxf(m, __shfl_xor(m, w, 64));
            const float e = expf(sc[i] - m);
            prob += e / wave_sum(e);
        }
        prob *= (1.0f / 3.0f);

        float best = prob;
        int   bidx = lane;
#pragma unroll
        for (int w = 32; w >= 1; w >>= 1) {
            const float ov = __shfl_xor(best, w, 64);
            const int   oi = __shfl_xor(bidx, w, 64);
            if (ov > best || (ov == best && oi < bidx)) { best = ov; bidx = oi; }
        }

        out[(size_t)N + (size_t)n * P + lane] = prob;
        if (lane == 0) out[n] = (float)proto_labels[cls * P + bidx];
    }
}

extern "C" void kernel_launch(void* const* d_in, const int* in_sizes, int n_in,
                              void* d_out, int out_size, void* d_ws, size_t ws_size,
                              hipStream_t stream) {
    const float* feats        = (const float*)d_in[0];
    const float* protos       = (const float*)d_in[1];
    const int*   cls_ids      = (const int*)d_in[2];
    const int*   proto_labels = (const int*)d_in[3];
    float* out = (float*)d_out;

    const int N    = in_sizes[2];            // 4096
    const int rows = in_sizes[1] / D;        // C*P
    const int C    = rows / P;               // 100

    char* w = (char*)d_ws;
    float* pp     = (float*)w;
    int*   sorted = (int*)(w + 25600);
    int*   desc   = (int*)(w + 41984);

    prep_kernel<<<1 + (rows + 3) / 4, 256, 0, stream>>>(
        protos, cls_ids, pp, sorted, desc, N, C, rows);
    proto_main_kernel<<<MAXD, 256, 0, stream>>>(
        feats, protos, proto_labels, pp, sorted, desc, out, N);
}